// Round 1
// baseline (1536.823 us; speedup 1.0000x reference)
//
#include <hip/hip_runtime.h>
#include <math.h>

// Problem constants
#define B_    64
#define S_    4096
#define HID   64
#define LIFT  256
#define MODES 16
#define NL    4

// Workspace layout (float offsets). Total = 17,108,992 floats ~= 68.5 MB.
#define OFF_H     0
#define OFF_TAB   (B_*HID*S_)            // 16777216 ; float2[4096] = 8192 floats
#define OFF_XFR   (OFF_TAB  + 8192)
#define OFF_XFI   (OFF_XFR  + B_*HID*MODES)   // 65536 each
#define OFF_YKR   (OFF_XFI  + B_*HID*MODES)
#define OFF_YKI   (OFF_YKR  + B_*HID*MODES)
#define OFF_W2T   (OFF_YKI  + B_*HID*MODES)
#define OFF_SKWT  (OFF_W2T  + LIFT*HID)       // 16384
#define OFF_PW1T  (OFF_SKWT + NL*HID*HID)     // 16384
#define OFF_PART  (OFF_PW1T + HID*LIFT)       // 16384 ; partials 64*64*3

__device__ __forceinline__ float gelu_f(float x) {
  return 0.5f * x * (1.0f + erff(x * 0.70710678118654752440f));
}

// ---------------------------------------------------------------- init ----
__global__ void k_init(const float* __restrict__ lift_w2,
                       const float* __restrict__ skip_w,
                       const float* __restrict__ proj_w1,
                       float* __restrict__ ws) {
  float2* tab  = (float2*)(ws + OFF_TAB);
  float*  w2T  = ws + OFF_W2T;
  float*  skwT = ws + OFF_SKWT;
  float*  pw1T = ws + OFF_PW1T;
  int idx = blockIdx.x * 256 + threadIdx.x;
  int stride = gridDim.x * 256;
  for (int k = idx; k < 4096; k += stride) {
    double th = (2.0 * 3.14159265358979323846 / 4096.0) * (double)k;
    double sn, cn; sincos(th, &sn, &cn);
    tab[k] = make_float2((float)cn, (float)sn);
  }
  for (int k = idx; k < LIFT * HID; k += stride) {     // w2T[c2][o]
    int c2 = k / HID, o = k % HID;
    w2T[k] = lift_w2[o * LIFT + c2];
  }
  for (int k = idx; k < NL * HID * HID; k += stride) { // skwT[l][c][o]
    int l = k / (HID * HID); int r = k % (HID * HID);
    int c = r / HID, o = r % HID;
    skwT[k] = skip_w[l * HID * HID + o * HID + c];
  }
  for (int k = idx; k < HID * LIFT; k += stride) {     // pw1T[c][c2]
    int c = k / LIFT, c2 = k % LIFT;
    pw1T[k] = proj_w1[c2 * HID + c];
  }
}

// ---------------------------------------------------------------- lift ----
// grid (S/32, B), block 256.  h[b][o][s] = b2[o] + sum_c2 w2[o][c2]*gelu(w1.x + b1)
__global__ __launch_bounds__(256) void k_lift(
    const float* __restrict__ x, const float* __restrict__ w1,
    const float* __restrict__ b1, const float* __restrict__ b2,
    const float* __restrict__ w2T, float* __restrict__ h) {
  __shared__ float xs[64];          // 32 s * 2 ch
  __shared__ float tl[256 * 36];    // t [c2][36] (padded, also reused as red)
  int tid = threadIdx.x;
  int b = blockIdx.y;
  int s0 = blockIdx.x * 32;
  if (tid < 64) xs[tid] = x[(b * S_ + s0) * 2 + tid];
  __syncthreads();
  { // phase A: t[c2][s] = gelu(...)
    float w10 = w1[tid * 2], w11 = w1[tid * 2 + 1], bb = b1[tid];
    #pragma unroll
    for (int sg = 0; sg < 8; ++sg) {
      float4 v;
      v.x = gelu_f(w10 * xs[(sg*4+0)*2] + w11 * xs[(sg*4+0)*2+1] + bb);
      v.y = gelu_f(w10 * xs[(sg*4+1)*2] + w11 * xs[(sg*4+1)*2+1] + bb);
      v.z = gelu_f(w10 * xs[(sg*4+2)*2] + w11 * xs[(sg*4+2)*2+1] + bb);
      v.w = gelu_f(w10 * xs[(sg*4+3)*2] + w11 * xs[(sg*4+3)*2+1] + bb);
      *(float4*)&tl[tid * 36 + sg * 4] = v;
    }
  }
  __syncthreads();
  // phase B: partial over c2 quarter
  int o = tid & 63, q = tid >> 6;
  float acc[32];
  #pragma unroll
  for (int s = 0; s < 32; ++s) acc[s] = 0.f;
  const float* wp = w2T + o;
  #pragma unroll 4
  for (int c2 = q * 64; c2 < q * 64 + 64; ++c2) {
    float w = wp[c2 * 64];
    #pragma unroll
    for (int sg = 0; sg < 8; ++sg) {
      float4 tv = *(const float4*)&tl[c2 * 36 + sg * 4];
      acc[sg*4+0] += w * tv.x; acc[sg*4+1] += w * tv.y;
      acc[sg*4+2] += w * tv.z; acc[sg*4+3] += w * tv.w;
    }
  }
  __syncthreads();
  #pragma unroll
  for (int sg = 0; sg < 8; ++sg)
    *(float4*)&tl[tid * 36 + sg * 4] =
        make_float4(acc[sg*4], acc[sg*4+1], acc[sg*4+2], acc[sg*4+3]);
  __syncthreads();
  // phase C: reduce 4 quarters, add bias, write out
  #pragma unroll
  for (int u = 0; u < 2; ++u) {
    int Q = tid + u * 256;           // 512 quads: o2 (64) x sq (8)
    int o2 = Q >> 3, sq = Q & 7;
    float4 r = make_float4(0.f, 0.f, 0.f, 0.f);
    #pragma unroll
    for (int qq = 0; qq < 4; ++qq) {
      float4 t = *(const float4*)&tl[(qq * 64 + o2) * 36 + sq * 4];
      r.x += t.x; r.y += t.y; r.z += t.z; r.w += t.w;
    }
    float bb = b2[o2];
    r.x += bb; r.y += bb; r.z += bb; r.w += bb;
    *(float4*)&h[(b * HID + o2) * S_ + s0 + sq * 4] = r;
  }
}

// --------------------------------------------------------- forward FFT ----
// grid (HID, B), block 256. xf[b,i,m] = sum_s h[b,i,s] e^{-2pi i m s/S}
__global__ __launch_bounds__(256) void k_fft_fwd(
    const float* __restrict__ h, const float2* __restrict__ tab,
    float* __restrict__ xfr, float* __restrict__ xfi) {
  int tid = threadIdx.x;
  int i = blockIdx.x, b = blockIdx.y;
  const float* hp = h + (b * HID + i) * S_ + tid;
  float a0 = 0.f;
  float ar[MODES], ai[MODES], pr[MODES], pi[MODES], rc[MODES], rs[MODES];
  #pragma unroll
  for (int m = 1; m < MODES; ++m) {
    ar[m] = 0.f; ai[m] = 0.f;
    float2 cs = tab[(m * tid) & 4095];
    pr[m] = cs.x; pi[m] = -cs.y;
    float2 rt = tab[m * 256];        // uniform -> scalar
    rc[m] = rt.x; rs[m] = -rt.y;
  }
  for (int k = 0; k < 16; ++k) {
    float hv = hp[k * 256];
    a0 += hv;
    #pragma unroll
    for (int m = 1; m < MODES; ++m) {
      ar[m] += hv * pr[m];
      ai[m] += hv * pi[m];
      float np = pr[m] * rc[m] - pi[m] * rs[m];
      pi[m]    = pr[m] * rs[m] + pi[m] * rc[m];
      pr[m] = np;
    }
  }
  // wave butterfly reduction
  #pragma unroll
  for (int off = 32; off > 0; off >>= 1) {
    a0 += __shfl_xor(a0, off, 64);
    #pragma unroll
    for (int m = 1; m < MODES; ++m) {
      ar[m] += __shfl_xor(ar[m], off, 64);
      ai[m] += __shfl_xor(ai[m], off, 64);
    }
  }
  __shared__ float red[4 * 32];
  int lane = tid & 63, wid = tid >> 6;
  if (lane == 0) {
    red[wid * 32 + 0] = a0;
    red[wid * 32 + 16] = 0.f;
    #pragma unroll
    for (int m = 1; m < MODES; ++m) {
      red[wid * 32 + m] = ar[m];
      red[wid * 32 + 16 + m] = ai[m];
    }
  }
  __syncthreads();
  if (tid < 32) {
    float s = red[tid] + red[32 + tid] + red[64 + tid] + red[96 + tid];
    int base = (b * HID + i) * MODES;
    if (tid < 16) xfr[base + tid] = s;
    else          xfi[base + tid - 16] = s;
  }
}

// ----------------------------------------------------------- mode mix ----
// grid B, block 256. yk[b,o,m] = sum_i xf[b,i,m]*w[i,o,m], pre-scaled for irfft
__global__ __launch_bounds__(256) void k_mix(
    const float* __restrict__ wr_, const float* __restrict__ wi_,
    const float* __restrict__ xfr, const float* __restrict__ xfi,
    float* __restrict__ ykr, float* __restrict__ yki) {
  int tid = threadIdx.x;
  int b = blockIdx.x;
  __shared__ float xr[HID * MODES], xi[HID * MODES];
  for (int u = tid; u < HID * MODES; u += 256) {
    xr[u] = xfr[b * HID * MODES + u];
    xi[u] = xfi[b * HID * MODES + u];
  }
  __syncthreads();
  const float invS = 1.0f / (float)S_;
  #pragma unroll
  for (int pp = 0; pp < 4; ++pp) {
    int p = tid + pp * 256;
    int o = p >> 4, m = p & 15;
    float yr = 0.f, yi = 0.f;
    for (int i2 = 0; i2 < HID; ++i2) {
      float wr = wr_[(i2 * HID + o) * MODES + m];
      float wi = wi_[(i2 * HID + o) * MODES + m];
      float xrv = xr[i2 * MODES + m], xiv = xi[i2 * MODES + m];
      yr += xrv * wr - xiv * wi;
      yi += xrv * wi + xiv * wr;
    }
    float fac = (m == 0) ? invS : 2.f * invS;
    ykr[(b * HID + o) * MODES + m] = yr * fac;
    yki[(b * HID + o) * MODES + m] = yi * fac;
  }
}

// --------------------------------------------- irfft + skip + (gelu) ----
// grid (S/64, B), block 256, in-place h update.
template <bool ACT>
__global__ __launch_bounds__(256) void k_spec_skip(
    const float* __restrict__ skwT, const float* __restrict__ skb,
    const float* __restrict__ ykr, const float* __restrict__ yki,
    const float2* __restrict__ tab, float* __restrict__ h) {
  __shared__ float hs[HID * 68];
  __shared__ float wsh[HID * HID];
  int tid = threadIdx.x;
  int s0 = blockIdx.x * 64, b = blockIdx.y;
  #pragma unroll
  for (int u = 0; u < 4; ++u) {
    int Q = tid + u * 256;           // 1024 quads: c(64) x sq(16)
    int c = Q >> 4, sq = Q & 15;
    *(float4*)&hs[c * 68 + sq * 4] =
        *(const float4*)&h[(b * HID + c) * S_ + s0 + sq * 4];
  }
  #pragma unroll
  for (int u = 0; u < 4; ++u)
    ((float4*)wsh)[tid + u * 256] = ((const float4*)skwT)[tid + u * 256];
  int o = tid & 63, q = tid >> 6;
  float br[MODES], bi[MODES];
  #pragma unroll
  for (int m = 0; m < MODES; ++m) {
    br[m] = ykr[(b * HID + o) * MODES + m];
    bi[m] = yki[(b * HID + o) * MODES + m];
  }
  float sb = skb[o];
  __syncthreads();
  float4 res[4];
  #pragma unroll
  for (int g = 0; g < 4; ++g) {
    int sl = q * 16 + g * 4;
    float acc[4];
    #pragma unroll
    for (int j = 0; j < 4; ++j) acc[j] = br[0] + sb;   // DC (Im(Y0) dropped) + bias
    #pragma unroll
    for (int m = 1; m < MODES; ++m) {
      #pragma unroll
      for (int j = 0; j < 4; ++j) {
        int idx = (m * (s0 + sl + j)) & 4095;          // wave-uniform
        idx = __builtin_amdgcn_readfirstlane(idx);
        float2 cs = tab[idx];
        acc[j] += br[m] * cs.x - bi[m] * cs.y;
      }
    }
    for (int c = 0; c < HID; ++c) {
      float w = wsh[c * 64 + o];
      float4 hv = *(const float4*)&hs[c * 68 + sl];    // uniform broadcast
      acc[0] += w * hv.x; acc[1] += w * hv.y;
      acc[2] += w * hv.z; acc[3] += w * hv.w;
    }
    if (ACT) {
      #pragma unroll
      for (int j = 0; j < 4; ++j) acc[j] = gelu_f(acc[j]);
    }
    res[g] = make_float4(acc[0], acc[1], acc[2], acc[3]);
  }
  __syncthreads();
  #pragma unroll
  for (int g = 0; g < 4; ++g)
    *(float4*)&hs[o * 68 + q * 16 + g * 4] = res[g];
  __syncthreads();
  #pragma unroll
  for (int u = 0; u < 4; ++u) {
    int Q = tid + u * 256;
    int c = Q >> 4, sq = Q & 15;
    *(float4*)&h[(b * HID + c) * S_ + s0 + sq * 4] =
        *(const float4*)&hs[c * 68 + sq * 4];
  }
}

// ------------------------------------------------- projection + mean ----
// grid (S/64, B), block 256 (thread = c2). Writes per-tile partial sums.
__global__ __launch_bounds__(256) void k_proj(
    const float* __restrict__ pw1T, const float* __restrict__ pb1,
    const float* __restrict__ pw2, const float* __restrict__ h,
    float* __restrict__ part) {
  __shared__ float hs[HID * 68];
  __shared__ float red[12];
  int tid = threadIdx.x;
  int s0 = blockIdx.x * 64, b = blockIdx.y;
  #pragma unroll
  for (int u = 0; u < 4; ++u) {
    int Q = tid + u * 256;
    int c = Q >> 4, sq = Q & 15;
    *(float4*)&hs[c * 68 + sq * 4] =
        *(const float4*)&h[(b * HID + c) * S_ + s0 + sq * 4];
  }
  __syncthreads();
  float tacc[64];
  #pragma unroll
  for (int s = 0; s < 64; ++s) tacc[s] = 0.f;
  #pragma unroll 2
  for (int c = 0; c < HID; ++c) {
    float w = pw1T[c * LIFT + tid];
    #pragma unroll
    for (int sg = 0; sg < 16; ++sg) {
      float4 hv = *(const float4*)&hs[c * 68 + sg * 4];
      tacc[sg*4+0] += w * hv.x; tacc[sg*4+1] += w * hv.y;
      tacc[sg*4+2] += w * hv.z; tacc[sg*4+3] += w * hv.w;
    }
  }
  float bb = pb1[tid];
  float p0 = pw2[tid], p1 = pw2[256 + tid], p2 = pw2[512 + tid];
  float o0 = 0.f, o1 = 0.f, o2 = 0.f;
  #pragma unroll
  for (int s = 0; s < 64; ++s) {
    float t = gelu_f(tacc[s] + bb);
    o0 += p0 * t; o1 += p1 * t; o2 += p2 * t;
  }
  #pragma unroll
  for (int off = 32; off > 0; off >>= 1) {
    o0 += __shfl_xor(o0, off, 64);
    o1 += __shfl_xor(o1, off, 64);
    o2 += __shfl_xor(o2, off, 64);
  }
  int lane = tid & 63, wid = tid >> 6;
  if (lane == 0) { red[wid*3+0] = o0; red[wid*3+1] = o1; red[wid*3+2] = o2; }
  __syncthreads();
  if (tid < 3) {
    float s = red[tid] + red[3 + tid] + red[6 + tid] + red[9 + tid];
    part[(b * 64 + blockIdx.x) * 3 + tid] = s;
  }
}

__global__ void k_final(const float* __restrict__ part,
                        const float* __restrict__ pb2,
                        float* __restrict__ out) {
  int t = threadIdx.x;
  if (t < B_ * 3) {
    int b = t / 3, j = t % 3;
    float s = 0.f;
    for (int k = 0; k < 64; ++k) s += part[(b * 64 + k) * 3 + j];
    out[t] = s * (1.0f / (float)S_) + pb2[j];
  }
}

// ------------------------------------------------------------- launch ----
extern "C" void kernel_launch(void* const* d_in, const int* in_sizes, int n_in,
                              void* d_out, int out_size, void* d_ws, size_t ws_size,
                              hipStream_t stream) {
  const float* x   = (const float*)d_in[0];
  const float* lw1 = (const float*)d_in[1];
  const float* lb1 = (const float*)d_in[2];
  const float* lw2 = (const float*)d_in[3];
  const float* lb2 = (const float*)d_in[4];
  const float* swr = (const float*)d_in[5];
  const float* swi = (const float*)d_in[6];
  const float* skw = (const float*)d_in[7];
  const float* skb = (const float*)d_in[8];
  const float* pw1 = (const float*)d_in[9];
  const float* pb1 = (const float*)d_in[10];
  const float* pw2 = (const float*)d_in[11];
  const float* pb2 = (const float*)d_in[12];
  float*  ws  = (float*)d_ws;
  float*  h   = ws + OFF_H;
  float2* tab = (float2*)(ws + OFF_TAB);

  k_init<<<64, 256, 0, stream>>>(lw2, skw, pw1, ws);
  k_lift<<<dim3(S_ / 32, B_), 256, 0, stream>>>(x, lw1, lb1, lb2,
                                                ws + OFF_W2T, h);
  for (int l = 0; l < NL; ++l) {
    k_fft_fwd<<<dim3(HID, B_), 256, 0, stream>>>(h, tab, ws + OFF_XFR,
                                                 ws + OFF_XFI);
    k_mix<<<B_, 256, 0, stream>>>(swr + l * HID * HID * MODES,
                                  swi + l * HID * HID * MODES,
                                  ws + OFF_XFR, ws + OFF_XFI,
                                  ws + OFF_YKR, ws + OFF_YKI);
    if (l < NL - 1)
      k_spec_skip<true><<<dim3(S_ / 64, B_), 256, 0, stream>>>(
          ws + OFF_SKWT + l * HID * HID, skb + l * HID,
          ws + OFF_YKR, ws + OFF_YKI, tab, h);
    else
      k_spec_skip<false><<<dim3(S_ / 64, B_), 256, 0, stream>>>(
          ws + OFF_SKWT + l * HID * HID, skb + l * HID,
          ws + OFF_YKR, ws + OFF_YKI, tab, h);
  }
  k_proj<<<dim3(S_ / 64, B_), 256, 0, stream>>>(ws + OFF_PW1T, pb1, pw2, h,
                                                ws + OFF_PART);
  k_final<<<1, 256, 0, stream>>>(ws + OFF_PART, pb2, (float*)d_out);
}

// Round 2
// 744.669 us; speedup vs baseline: 2.0638x; 2.0638x over previous
//
#include <hip/hip_runtime.h>
#include <math.h>

// Problem constants
#define B_    64
#define S_    4096
#define HID   64
#define LIFT  256
#define MODES 16
#define NL    4

// Workspace layout (float offsets).
#define OFF_H     0
#define OFF_TAB   (B_*HID*S_)                 // float2[4096] = 8192 floats
#define OFF_XFR   (OFF_TAB  + 8192)
#define OFF_XFI   (OFF_XFR  + B_*HID*MODES)   // 65536 each
#define OFF_YKR   (OFF_XFI  + B_*HID*MODES)
#define OFF_YKI   (OFF_YKR  + B_*HID*MODES)
#define OFF_W2T   (OFF_YKI  + B_*HID*MODES)
#define OFF_SKWT  (OFF_W2T  + LIFT*HID)       // 16384
#define OFF_PW1T  (OFF_SKWT + NL*HID*HID)     // 16384
#define OFF_PART  (OFF_PW1T + HID*LIFT)       // 24576 floats: 64*32*4*3

__device__ __forceinline__ float gelu_f(float x) {
  return 0.5f * x * (1.0f + erff(x * 0.70710678118654752440f));
}

// ---------------------------------------------------------------- init ----
__global__ void k_init(const float* __restrict__ lift_w2,
                       const float* __restrict__ skip_w,
                       const float* __restrict__ proj_w1,
                       float* __restrict__ ws) {
  float2* tab  = (float2*)(ws + OFF_TAB);
  float*  w2T  = ws + OFF_W2T;
  float*  skwT = ws + OFF_SKWT;
  float*  pw1T = ws + OFF_PW1T;
  int idx = blockIdx.x * 256 + threadIdx.x;
  int stride = gridDim.x * 256;
  for (int k = idx; k < 4096; k += stride) {
    double th = (2.0 * 3.14159265358979323846 / 4096.0) * (double)k;
    double sn, cn; sincos(th, &sn, &cn);
    tab[k] = make_float2((float)cn, (float)sn);
  }
  for (int k = idx; k < LIFT * HID; k += stride) {     // w2T[c2][o]
    int c2 = k / HID, o = k % HID;
    w2T[k] = lift_w2[o * LIFT + c2];
  }
  for (int k = idx; k < NL * HID * HID; k += stride) { // skwT[l][c][o]
    int l = k / (HID * HID); int r = k % (HID * HID);
    int c = r / HID, o = r % HID;
    skwT[k] = skip_w[l * HID * HID + o * HID + c];
  }
  for (int k = idx; k < HID * LIFT; k += stride) {     // pw1T[c][c2]
    int c = k / LIFT, c2 = k % LIFT;
    pw1T[k] = proj_w1[c2 * HID + c];
  }
}

// ---------------------------------------------------------------- lift ----
// grid (S/128, B), block 256. h[b][o][s] = b2[o] + sum_c2 w2T[c2][o]*gelu(...)
// wave owns 16 o rows (scalar W loads); lane owns 2 s columns.
__global__ __launch_bounds__(256) void k_lift(
    const float* __restrict__ x, const float* __restrict__ w1,
    const float* __restrict__ b1, const float* __restrict__ b2,
    const float* __restrict__ w2T, float* __restrict__ h) {
  __shared__ float x0[128], x1[128];
  __shared__ float Tl[64 * 128];
  int tid = threadIdx.x;
  int b = blockIdx.y;
  int s0 = blockIdx.x * 128;
  const int wo = __builtin_amdgcn_readfirstlane((tid >> 6) << 4);
  const int sl = (tid & 63) * 2;
  if (tid < 128) {
    float2 v = ((const float2*)x)[b * S_ + s0 + tid];
    x0[tid] = v.x; x1[tid] = v.y;
  }
  float acc[16][2];
  #pragma unroll
  for (int o = 0; o < 16; ++o) { acc[o][0] = 0.f; acc[o][1] = 0.f; }

  for (int ch = 0; ch < 4; ++ch) {
    __syncthreads();
    // compute gelu tile chunk: c2 = ch*64 + c2l
    int sq = (tid & 31) * 4;
    #pragma unroll
    for (int i = 0; i < 8; ++i) {
      int c2l = i * 8 + (tid >> 5);
      int c2 = ch * 64 + c2l;
      float2 wv = ((const float2*)w1)[c2];
      float bb = b1[c2];
      float4 xv0 = *(const float4*)&x0[sq];
      float4 xv1 = *(const float4*)&x1[sq];
      float4 tv;
      tv.x = gelu_f(wv.x * xv0.x + wv.y * xv1.x + bb);
      tv.y = gelu_f(wv.x * xv0.y + wv.y * xv1.y + bb);
      tv.z = gelu_f(wv.x * xv0.z + wv.y * xv1.z + bb);
      tv.w = gelu_f(wv.x * xv0.w + wv.y * xv1.w + bb);
      *(float4*)&Tl[c2l * 128 + sq] = tv;
    }
    __syncthreads();
    // GEMM over this K-chunk
    #pragma unroll 4
    for (int c = 0; c < 64; ++c) {
      const float* __restrict__ wrow = w2T + (ch * 64 + c) * 64 + wo;
      float w[16];
      #pragma unroll
      for (int o = 0; o < 16; ++o) w[o] = wrow[o];
      float2 hv = *(const float2*)&Tl[c * 128 + sl];
      #pragma unroll
      for (int o = 0; o < 16; ++o) {
        acc[o][0] += w[o] * hv.x;
        acc[o][1] += w[o] * hv.y;
      }
    }
  }
  // epilogue: bias, write back via LDS
  {
    const float* __restrict__ brow = b2 + wo;
    float bb[16];
    #pragma unroll
    for (int o = 0; o < 16; ++o) bb[o] = brow[o];
    __syncthreads();
    #pragma unroll
    for (int o = 0; o < 16; ++o)
      *(float2*)&Tl[(wo + o) * 128 + sl] =
          make_float2(acc[o][0] + bb[o], acc[o][1] + bb[o]);
    __syncthreads();
    #pragma unroll
    for (int i = 0; i < 8; ++i) {
      int c = i * 8 + (tid >> 5);
      int sq = (tid & 31) * 4;
      *(float4*)&h[(b * HID + c) * S_ + s0 + sq] = *(const float4*)&Tl[c * 128 + sq];
    }
  }
}

// --------------------------------------------------------- forward FFT ----
// grid (HID, B), block 256. xf[b,i,m] = sum_s h[b,i,s] e^{-2pi i m s/S}
__global__ __launch_bounds__(256) void k_fft_fwd(
    const float* __restrict__ h, const float2* __restrict__ tab,
    float* __restrict__ xfr, float* __restrict__ xfi) {
  int tid = threadIdx.x;
  int i = blockIdx.x, b = blockIdx.y;
  const float* hp = h + (b * HID + i) * S_ + tid;
  float a0 = 0.f;
  float ar[MODES], ai[MODES], pr[MODES], pi[MODES], rc[MODES], rs[MODES];
  #pragma unroll
  for (int m = 1; m < MODES; ++m) {
    ar[m] = 0.f; ai[m] = 0.f;
    float2 cs = tab[(m * tid) & 4095];
    pr[m] = cs.x; pi[m] = -cs.y;
    float2 rt = tab[m * 256];        // uniform -> scalar
    rc[m] = rt.x; rs[m] = -rt.y;
  }
  for (int k = 0; k < 16; ++k) {
    float hv = hp[k * 256];
    a0 += hv;
    #pragma unroll
    for (int m = 1; m < MODES; ++m) {
      ar[m] += hv * pr[m];
      ai[m] += hv * pi[m];
      float np = pr[m] * rc[m] - pi[m] * rs[m];
      pi[m]    = pr[m] * rs[m] + pi[m] * rc[m];
      pr[m] = np;
    }
  }
  #pragma unroll
  for (int off = 32; off > 0; off >>= 1) {
    a0 += __shfl_xor(a0, off, 64);
    #pragma unroll
    for (int m = 1; m < MODES; ++m) {
      ar[m] += __shfl_xor(ar[m], off, 64);
      ai[m] += __shfl_xor(ai[m], off, 64);
    }
  }
  __shared__ float red[4 * 32];
  int lane = tid & 63, wid = tid >> 6;
  if (lane == 0) {
    red[wid * 32 + 0] = a0;
    red[wid * 32 + 16] = 0.f;
    #pragma unroll
    for (int m = 1; m < MODES; ++m) {
      red[wid * 32 + m] = ar[m];
      red[wid * 32 + 16 + m] = ai[m];
    }
  }
  __syncthreads();
  if (tid < 32) {
    float s = red[tid] + red[32 + tid] + red[64 + tid] + red[96 + tid];
    int base = (b * HID + i) * MODES;
    if (tid < 16) xfr[base + tid] = s;
    else          xfi[base + tid - 16] = s;
  }
}

// ----------------------------------------------------------- mode mix ----
// grid (4, B), block 256. yk[b][m][o] = fac * sum_i xf[b,i,m]*w[i,o,m]
__global__ __launch_bounds__(256) void k_mix(
    const float* __restrict__ wr_, const float* __restrict__ wi_,
    const float* __restrict__ xfr, const float* __restrict__ xfi,
    float* __restrict__ ykr, float* __restrict__ yki) {
  int tid = threadIdx.x;
  int b = blockIdx.y, pp = blockIdx.x;
  __shared__ float xr[HID * MODES], xi[HID * MODES];
  for (int u = tid; u < HID * MODES; u += 256) {
    xr[u] = xfr[b * HID * MODES + u];
    xi[u] = xfi[b * HID * MODES + u];
  }
  __syncthreads();
  const float invS = 1.0f / (float)S_;
  int o = pp * 16 + (tid >> 4), m = tid & 15;
  float yr = 0.f, yi = 0.f;
  for (int i2 = 0; i2 < HID; ++i2) {
    float wr = wr_[(i2 * HID + o) * MODES + m];
    float wi = wi_[(i2 * HID + o) * MODES + m];
    float xrv = xr[i2 * MODES + m], xiv = xi[i2 * MODES + m];
    yr += xrv * wr - xiv * wi;
    yi += xrv * wi + xiv * wr;
  }
  float fac = (m == 0) ? invS : 2.f * invS;
  ykr[(b * 16 + m) * 64 + o] = yr * fac;
  yki[(b * 16 + m) * 64 + o] = yi * fac;
}

// --------------------------------------------- irfft + skip + (gelu) ----
// grid (S/128, B), block 256, in-place h update.
// acc[o][s] = skb[o] + sum_m (Yr[m][o]cos - Yi[m][o]sin) + sum_c W[c][o] h[c][s]
template <bool ACT>
__global__ __launch_bounds__(256) void k_spec_skip(
    const float* __restrict__ skwT, const float* __restrict__ skb,
    const float* __restrict__ ykr, const float* __restrict__ yki,
    const float2* __restrict__ tab, float* __restrict__ h) {
  __shared__ float hs[64 * 128];   // 32 KB
  __shared__ float Tc[16 * 128];   // cos rows, 8 KB
  __shared__ float Ts[16 * 128];   // -sin rows, 8 KB
  int tid = threadIdx.x;
  int s0 = blockIdx.x * 128, b = blockIdx.y;
  const int wo = __builtin_amdgcn_readfirstlane((tid >> 6) << 4);
  const int sl = (tid & 63) * 2;
  // stage h tile (flat per-row copies, coalesced, conflict-free)
  #pragma unroll
  for (int i = 0; i < 8; ++i) {
    int c = i * 8 + (tid >> 5);
    int sq = (tid & 31) * 4;
    *(float4*)&hs[c * 128 + sq] = *(const float4*)&h[(b * HID + c) * S_ + s0 + sq];
  }
  // stage twiddle rows
  {
    int m = tid >> 4, ss = (tid & 15) * 8;
    #pragma unroll
    for (int i = 0; i < 8; ++i) {
      int s = s0 + ss + i;
      float2 cs = tab[(m * s) & 4095];
      Tc[m * 128 + ss + i] = cs.x;
      Ts[m * 128 + ss + i] = -cs.y;
    }
  }
  float acc[16][2];
  {
    const float* __restrict__ brow = skb + wo;
    #pragma unroll
    for (int o = 0; o < 16; ++o) { acc[o][0] = brow[o]; acc[o][1] = brow[o]; }
  }
  __syncthreads();
  // spectral part: K = 32 (16 cos rows with Yr, 16 -sin rows with Yi)
  #pragma unroll 2
  for (int m = 0; m < 16; ++m) {
    const float* __restrict__ yrow = ykr + (b * 16 + m) * 64 + wo;
    float w[16];
    #pragma unroll
    for (int o = 0; o < 16; ++o) w[o] = yrow[o];
    float2 tv = *(const float2*)&Tc[m * 128 + sl];
    #pragma unroll
    for (int o = 0; o < 16; ++o) {
      acc[o][0] += w[o] * tv.x;
      acc[o][1] += w[o] * tv.y;
    }
  }
  #pragma unroll 2
  for (int m = 0; m < 16; ++m) {
    const float* __restrict__ yrow = yki + (b * 16 + m) * 64 + wo;
    float w[16];
    #pragma unroll
    for (int o = 0; o < 16; ++o) w[o] = yrow[o];
    float2 tv = *(const float2*)&Ts[m * 128 + sl];
    #pragma unroll
    for (int o = 0; o < 16; ++o) {
      acc[o][0] += w[o] * tv.x;
      acc[o][1] += w[o] * tv.y;
    }
  }
  // skip GEMM: K = 64
  #pragma unroll 4
  for (int c = 0; c < 64; ++c) {
    const float* __restrict__ wrow = skwT + c * 64 + wo;
    float w[16];
    #pragma unroll
    for (int o = 0; o < 16; ++o) w[o] = wrow[o];
    float2 hv = *(const float2*)&hs[c * 128 + sl];
    #pragma unroll
    for (int o = 0; o < 16; ++o) {
      acc[o][0] += w[o] * hv.x;
      acc[o][1] += w[o] * hv.y;
    }
  }
  if (ACT) {
    #pragma unroll
    for (int o = 0; o < 16; ++o) {
      acc[o][0] = gelu_f(acc[o][0]);
      acc[o][1] = gelu_f(acc[o][1]);
    }
  }
  __syncthreads();
  #pragma unroll
  for (int o = 0; o < 16; ++o)
    *(float2*)&hs[(wo + o) * 128 + sl] = make_float2(acc[o][0], acc[o][1]);
  __syncthreads();
  #pragma unroll
  for (int i = 0; i < 8; ++i) {
    int c = i * 8 + (tid >> 5);
    int sq = (tid & 31) * 4;
    *(float4*)&h[(b * HID + c) * S_ + s0 + sq] = *(const float4*)&hs[c * 128 + sq];
  }
}

// ------------------------------------------------- projection + mean ----
// grid (S/128, B, 4). Block handles 64 c2-rows (z picks which) x 128 s.
__global__ __launch_bounds__(256) void k_proj(
    const float* __restrict__ pw1T, const float* __restrict__ pb1,
    const float* __restrict__ pw2, const float* __restrict__ h,
    float* __restrict__ part) {
  __shared__ float hs[64 * 128];
  __shared__ float red[12];
  int tid = threadIdx.x;
  int s0 = blockIdx.x * 128, b = blockIdx.y;
  int c2base = blockIdx.z * 64;
  const int wo = __builtin_amdgcn_readfirstlane((tid >> 6) << 4);
  const int sl = (tid & 63) * 2;
  #pragma unroll
  for (int i = 0; i < 8; ++i) {
    int c = i * 8 + (tid >> 5);
    int sq = (tid & 31) * 4;
    *(float4*)&hs[c * 128 + sq] = *(const float4*)&h[(b * HID + c) * S_ + s0 + sq];
  }
  float acc[16][2];
  #pragma unroll
  for (int o = 0; o < 16; ++o) { acc[o][0] = 0.f; acc[o][1] = 0.f; }
  __syncthreads();
  #pragma unroll 4
  for (int c = 0; c < 64; ++c) {
    const float* __restrict__ wrow = pw1T + c * LIFT + c2base + wo;
    float w[16];
    #pragma unroll
    for (int o = 0; o < 16; ++o) w[o] = wrow[o];
    float2 hv = *(const float2*)&hs[c * 128 + sl];
    #pragma unroll
    for (int o = 0; o < 16; ++o) {
      acc[o][0] += w[o] * hv.x;
      acc[o][1] += w[o] * hv.y;
    }
  }
  // epilogue: gelu + contract with pw2, reduce over s and c2
  const float* __restrict__ b1row = pb1 + c2base + wo;
  const float* __restrict__ p0row = pw2 + c2base + wo;
  const float* __restrict__ p1row = pw2 + 256 + c2base + wo;
  const float* __restrict__ p2row = pw2 + 512 + c2base + wo;
  float o0 = 0.f, o1 = 0.f, o2 = 0.f;
  #pragma unroll
  for (int o = 0; o < 16; ++o) {
    float bb = b1row[o];
    float t = gelu_f(acc[o][0] + bb) + gelu_f(acc[o][1] + bb);
    o0 += p0row[o] * t; o1 += p1row[o] * t; o2 += p2row[o] * t;
  }
  #pragma unroll
  for (int off = 32; off > 0; off >>= 1) {
    o0 += __shfl_xor(o0, off, 64);
    o1 += __shfl_xor(o1, off, 64);
    o2 += __shfl_xor(o2, off, 64);
  }
  int lane = tid & 63, wid = tid >> 6;
  if (lane == 0) { red[wid*3+0] = o0; red[wid*3+1] = o1; red[wid*3+2] = o2; }
  __syncthreads();
  if (tid < 3) {
    float s = red[tid] + red[3 + tid] + red[6 + tid] + red[9 + tid];
    part[((b * 32 + blockIdx.x) * 4 + blockIdx.z) * 3 + tid] = s;
  }
}

__global__ void k_final(const float* __restrict__ part,
                        const float* __restrict__ pb2,
                        float* __restrict__ out) {
  int t = threadIdx.x;
  if (t < B_ * 3) {
    int b = t / 3, j = t % 3;
    float s = 0.f;
    for (int k = 0; k < 128; ++k) s += part[(b * 128 + k) * 3 + j];
    out[t] = s * (1.0f / (float)S_) + pb2[j];
  }
}

// ------------------------------------------------------------- launch ----
extern "C" void kernel_launch(void* const* d_in, const int* in_sizes, int n_in,
                              void* d_out, int out_size, void* d_ws, size_t ws_size,
                              hipStream_t stream) {
  const float* x   = (const float*)d_in[0];
  const float* lw1 = (const float*)d_in[1];
  const float* lb1 = (const float*)d_in[2];
  const float* lw2 = (const float*)d_in[3];
  const float* lb2 = (const float*)d_in[4];
  const float* swr = (const float*)d_in[5];
  const float* swi = (const float*)d_in[6];
  const float* skw = (const float*)d_in[7];
  const float* skb = (const float*)d_in[8];
  const float* pw1 = (const float*)d_in[9];
  const float* pb1 = (const float*)d_in[10];
  const float* pw2 = (const float*)d_in[11];
  const float* pb2 = (const float*)d_in[12];
  float*  ws  = (float*)d_ws;
  float*  h   = ws + OFF_H;
  float2* tab = (float2*)(ws + OFF_TAB);

  k_init<<<64, 256, 0, stream>>>(lw2, skw, pw1, ws);
  k_lift<<<dim3(S_ / 128, B_), 256, 0, stream>>>(x, lw1, lb1, lb2,
                                                 ws + OFF_W2T, h);
  for (int l = 0; l < NL; ++l) {
    k_fft_fwd<<<dim3(HID, B_), 256, 0, stream>>>(h, tab, ws + OFF_XFR,
                                                 ws + OFF_XFI);
    k_mix<<<dim3(4, B_), 256, 0, stream>>>(swr + l * HID * HID * MODES,
                                           swi + l * HID * HID * MODES,
                                           ws + OFF_XFR, ws + OFF_XFI,
                                           ws + OFF_YKR, ws + OFF_YKI);
    if (l < NL - 1)
      k_spec_skip<true><<<dim3(S_ / 128, B_), 256, 0, stream>>>(
          ws + OFF_SKWT + l * HID * HID, skb + l * HID,
          ws + OFF_YKR, ws + OFF_YKI, tab, h);
    else
      k_spec_skip<false><<<dim3(S_ / 128, B_), 256, 0, stream>>>(
          ws + OFF_SKWT + l * HID * HID, skb + l * HID,
          ws + OFF_YKR, ws + OFF_YKI, tab, h);
  }
  k_proj<<<dim3(S_ / 128, B_, 4), 256, 0, stream>>>(ws + OFF_PW1T, pb1, pw2, h,
                                                    ws + OFF_PART);
  k_final<<<1, 256, 0, stream>>>(ws + OFF_PART, pb2, (float*)d_out);
}